// Round 1
// baseline (758.048 us; speedup 1.0000x reference)
//
#include <hip/hip_runtime.h>
#include <hip/hip_bf16.h>

// Problem constants (derived at launch from in_sizes where possible)
// N=50000, E=800000, D=128, H=8, HD=16, ED=16

#define DMODEL 128
#define NHEAD 8
#define HDIM 16
#define EDIM 16

// ---------------------------------------------------------------------------
// Tiled fp32 GEMM: C[M,128] = A[M,128] @ B[128,128] + bias[128]
// 64x64 tile, 256 threads, full K=128 staged in LDS.
// ---------------------------------------------------------------------------
__global__ __launch_bounds__(256) void gemm_f32_128(
    const float* __restrict__ A, const float* __restrict__ B,
    const float* __restrict__ bias, float* __restrict__ C, int M) {
  __shared__ float As[64][132];   // padded stride (132 = 4*33, float4-aligned)
  __shared__ float Bs[128][64];

  const int row0 = blockIdx.x * 64;
  const int col0 = blockIdx.y * 64;
  const int tid = threadIdx.x;

  // Load A tile: 64 rows x 128 cols = 2048 float4 -> 8 per thread
  #pragma unroll
  for (int i = 0; i < 8; ++i) {
    int idx = tid + i * 256;
    int r = idx >> 5;        // 32 float4 per row
    int c4 = idx & 31;
    int gr = row0 + r;
    float4 vv = make_float4(0.f, 0.f, 0.f, 0.f);
    if (gr < M) vv = *(const float4*)(A + (size_t)gr * DMODEL + c4 * 4);
    *(float4*)&As[r][c4 * 4] = vv;
  }
  // Load B tile: 128 rows x 64 cols = 2048 float4 -> 8 per thread
  #pragma unroll
  for (int i = 0; i < 8; ++i) {
    int idx = tid + i * 256;
    int r = idx >> 4;        // 16 float4 per row
    int c4 = idx & 15;
    *(float4*)&Bs[r][c4 * 4] = *(const float4*)(B + (size_t)r * DMODEL + col0 + c4 * 4);
  }
  __syncthreads();

  const int ty = tid >> 4;   // 0..15
  const int tx = tid & 15;   // 0..15
  float acc[4][4] = {};

  #pragma unroll 4
  for (int k = 0; k < 128; ++k) {
    float a0 = As[ty * 4 + 0][k];
    float a1 = As[ty * 4 + 1][k];
    float a2 = As[ty * 4 + 2][k];
    float a3 = As[ty * 4 + 3][k];
    float4 b = *(float4*)&Bs[k][tx * 4];
    acc[0][0] += a0 * b.x; acc[0][1] += a0 * b.y; acc[0][2] += a0 * b.z; acc[0][3] += a0 * b.w;
    acc[1][0] += a1 * b.x; acc[1][1] += a1 * b.y; acc[1][2] += a1 * b.z; acc[1][3] += a1 * b.w;
    acc[2][0] += a2 * b.x; acc[2][1] += a2 * b.y; acc[2][2] += a2 * b.z; acc[2][3] += a2 * b.w;
    acc[3][0] += a3 * b.x; acc[3][1] += a3 * b.y; acc[3][2] += a3 * b.z; acc[3][3] += a3 * b.w;
  }

  // Epilogue: add bias, float4 stores
  const int gc = col0 + tx * 4;
  float4 bs = *(const float4*)(bias + gc);
  #pragma unroll
  for (int i = 0; i < 4; ++i) {
    int gr = row0 + ty * 4 + i;
    if (gr < M) {
      float4 o;
      o.x = acc[i][0] + bs.x;
      o.y = acc[i][1] + bs.y;
      o.z = acc[i][2] + bs.z;
      o.w = acc[i][3] + bs.w;
      *(float4*)(C + (size_t)gr * DMODEL + gc) = o;
    }
  }
}

// ---------------------------------------------------------------------------
// CSR build: count, scan, fill
// ---------------------------------------------------------------------------
__global__ void count_kernel(const int* __restrict__ dst, int* __restrict__ counts, int E) {
  int e = blockIdx.x * blockDim.x + threadIdx.x;
  if (e < E) atomicAdd(&counts[dst[e]], 1);
}

__global__ __launch_bounds__(1024) void scan_kernel(const int* __restrict__ counts,
                                                    int* __restrict__ row_start, int n) {
  __shared__ int lds[1024];
  __shared__ int carry;
  if (threadIdx.x == 0) { carry = 0; row_start[0] = 0; }
  __syncthreads();
  for (int base = 0; base < n; base += 1024) {
    int i = base + threadIdx.x;
    int val = (i < n) ? counts[i] : 0;
    lds[threadIdx.x] = val;
    __syncthreads();
    for (int off = 1; off < 1024; off <<= 1) {
      int t = (threadIdx.x >= off) ? lds[threadIdx.x - off] : 0;
      __syncthreads();
      lds[threadIdx.x] += t;
      __syncthreads();
    }
    if (i < n) row_start[i + 1] = carry + lds[threadIdx.x];
    __syncthreads();
    if (threadIdx.x == 0) carry += lds[1023];
    __syncthreads();
  }
}

__global__ void fill_kernel(const int* __restrict__ dst, const int* __restrict__ row_start,
                            int* __restrict__ cursor, int* __restrict__ edge_list, int E) {
  int e = blockIdx.x * blockDim.x + threadIdx.x;
  if (e < E) {
    int d = dst[e];
    int p = atomicAdd(&cursor[d], 1);
    edge_list[row_start[d] + p] = e;
  }
}

// ---------------------------------------------------------------------------
// Edge scores: 8 lanes per edge (lane = head).
// score[e,h] = dot(k[src,h,:], q[dst,h,:]) * 0.25 + (e_feat[e] @ We)[h] + be[h]
// Also atomicMax into monotone-uint segment max per (dst, head).
// ---------------------------------------------------------------------------
__device__ __forceinline__ unsigned fmax_map(float f) {
  unsigned u = __float_as_uint(f);
  return (u & 0x80000000u) ? ~u : (u | 0x80000000u);
}
__device__ __forceinline__ float fmax_unmap(unsigned u) {
  return __uint_as_float((u & 0x80000000u) ? (u & 0x7FFFFFFFu) : ~u);
}

__global__ __launch_bounds__(256) void score_kernel(
    const float* __restrict__ kmat, const float* __restrict__ qmat,
    const float* __restrict__ e_feat, const float* __restrict__ We,
    const float* __restrict__ be, const int* __restrict__ src,
    const int* __restrict__ dst, float* __restrict__ score,
    unsigned* __restrict__ smax, int E) {
  int gid = blockIdx.x * blockDim.x + threadIdx.x;
  int e = gid >> 3;
  int h = gid & 7;
  if (e >= E) return;
  int s = src[e];
  int d = dst[e];

  const float4* kp = (const float4*)(kmat + (size_t)s * DMODEL + h * HDIM);
  const float4* qp = (const float4*)(qmat + (size_t)d * DMODEL + h * HDIM);
  float dot = 0.f;
  #pragma unroll
  for (int i = 0; i < 4; ++i) {
    float4 kv = kp[i];
    float4 qv = qp[i];
    dot += kv.x * qv.x + kv.y * qv.y + kv.z * qv.z + kv.w * qv.w;
  }
  float sc = dot * 0.25f;  // HD^-0.5 = 16^-0.5

  // edge bias
  const float4* ep = (const float4*)(e_feat + (size_t)e * EDIM);
  float eb = be[h];
  #pragma unroll
  for (int i = 0; i < 4; ++i) {
    float4 ev = ep[i];
    eb += ev.x * We[(i * 4 + 0) * NHEAD + h];
    eb += ev.y * We[(i * 4 + 1) * NHEAD + h];
    eb += ev.z * We[(i * 4 + 2) * NHEAD + h];
    eb += ev.w * We[(i * 4 + 3) * NHEAD + h];
  }
  sc += eb;

  score[(size_t)e * NHEAD + h] = sc;
  atomicMax(&smax[(size_t)d * NHEAD + h], fmax_map(sc));
}

// ---------------------------------------------------------------------------
// exp(score - smax[dst]) in place + denom atomicAdd
// ---------------------------------------------------------------------------
__global__ __launch_bounds__(256) void exp_kernel(
    float* __restrict__ score, const unsigned* __restrict__ smax,
    const int* __restrict__ dst, float* __restrict__ denom, int E) {
  int gid = blockIdx.x * blockDim.x + threadIdx.x;
  int e = gid >> 3;
  int h = gid & 7;
  if (e >= E) return;
  int d = dst[e];
  float mf = fmax_unmap(smax[(size_t)d * NHEAD + h]);
  float ex = __expf(score[gid]) * 0.f;  // placeholder avoided; compute properly below
  ex = expf(score[gid] - mf);
  score[gid] = ex;
  atomicAdd(&denom[(size_t)d * NHEAD + h], ex);
}

// ---------------------------------------------------------------------------
// Per-node gather aggregation: out_pre[n,t] = sum_e a[e, t/16] * v[src_e, t]
// One 128-thread block per node.
// ---------------------------------------------------------------------------
__global__ __launch_bounds__(128) void agg_kernel(
    const float* __restrict__ vmat, const float* __restrict__ ex,
    const float* __restrict__ denom, const int* __restrict__ row_start,
    const int* __restrict__ edge_list, const int* __restrict__ src,
    float* __restrict__ out_pre, int N) {
  int n = blockIdx.x;
  int t = threadIdx.x;
  int h = t >> 4;
  __shared__ float rden[NHEAD];
  if (t < NHEAD) {
    float dn = denom[(size_t)n * NHEAD + t];
    rden[t] = (dn > 0.f) ? 1.0f / dn : 0.0f;
  }
  __syncthreads();
  const float rd = rden[h];
  int e0 = row_start[n];
  int e1 = row_start[n + 1];
  float acc = 0.f;
  for (int i = e0; i < e1; ++i) {
    int e = edge_list[i];
    int s = src[e];
    float a = ex[(size_t)e * NHEAD + h] * rd;
    acc += vmat[(size_t)s * DMODEL + t] * a;
  }
  out_pre[(size_t)n * DMODEL + t] = acc;
}

// ---------------------------------------------------------------------------
// Launch
// ---------------------------------------------------------------------------
extern "C" void kernel_launch(void* const* d_in, const int* in_sizes, int n_in,
                              void* d_out, int out_size, void* d_ws, size_t ws_size,
                              hipStream_t stream) {
  const float* h_in  = (const float*)d_in[0];
  const int*   src   = (const int*)d_in[1];
  const int*   dst   = (const int*)d_in[2];
  const float* e_feat= (const float*)d_in[3];
  const float* Wq    = (const float*)d_in[4];
  const float* bq    = (const float*)d_in[5];
  const float* Wk    = (const float*)d_in[6];
  const float* bk    = (const float*)d_in[7];
  const float* Wv    = (const float*)d_in[8];
  const float* bv    = (const float*)d_in[9];
  const float* We    = (const float*)d_in[10];
  const float* be    = (const float*)d_in[11];
  const float* Wo    = (const float*)d_in[12];
  const float* bo    = (const float*)d_in[13];
  float* out = (float*)d_out;

  const int N = in_sizes[0] / DMODEL;
  const int E = in_sizes[1];

  // Workspace layout
  char* ws = (char*)d_ws;
  size_t off = 0;
  auto alloc = [&](size_t bytes) {
    size_t o = off;
    off = (off + bytes + 255) & ~(size_t)255;
    return o;
  };
  float*    q        = (float*)(ws + alloc((size_t)N * DMODEL * 4));
  float*    k        = (float*)(ws + alloc((size_t)N * DMODEL * 4));
  float*    v        = (float*)(ws + alloc((size_t)N * DMODEL * 4));
  float*    score    = (float*)(ws + alloc((size_t)E * NHEAD * 4));
  unsigned* smax     = (unsigned*)(ws + alloc((size_t)N * NHEAD * 4));
  float*    denom    = (float*)(ws + alloc((size_t)N * NHEAD * 4));
  int*      counts   = (int*)(ws + alloc((size_t)N * 4));
  int*      row_start= (int*)(ws + alloc((size_t)(N + 1) * 4));
  int*      cursor   = (int*)(ws + alloc((size_t)N * 4));
  int*      edge_list= (int*)(ws + alloc((size_t)E * 4));
  float*    out_pre  = (float*)(ws + alloc((size_t)N * DMODEL * 4));
  (void)ws_size;

  // Zero-init accumulators (ws is poisoned 0xAA before every timed call)
  hipMemsetAsync(smax,   0, (size_t)N * NHEAD * 4, stream);
  hipMemsetAsync(denom,  0, (size_t)N * NHEAD * 4, stream);
  hipMemsetAsync(counts, 0, (size_t)N * 4, stream);
  hipMemsetAsync(cursor, 0, (size_t)N * 4, stream);

  const int rowTiles = (N + 63) / 64;

  // QKV projections
  {
    dim3 grid(rowTiles, 2);
    gemm_f32_128<<<grid, 256, 0, stream>>>(h_in, Wq, bq, q, N);
    gemm_f32_128<<<grid, 256, 0, stream>>>(h_in, Wk, bk, k, N);
    gemm_f32_128<<<grid, 256, 0, stream>>>(h_in, Wv, bv, v, N);
  }

  // CSR build (independent of QKV; serialized on stream is fine)
  {
    int blocks = (E + 255) / 256;
    count_kernel<<<blocks, 256, 0, stream>>>(dst, counts, E);
    scan_kernel<<<1, 1024, 0, stream>>>(counts, row_start, N);
    fill_kernel<<<blocks, 256, 0, stream>>>(dst, row_start, cursor, edge_list, E);
  }

  // Edge scores + segment max
  {
    int threads = E * NHEAD;
    int blocks = (threads + 255) / 256;
    score_kernel<<<blocks, 256, 0, stream>>>(k, q, e_feat, We, be, src, dst, score, smax, E);
    exp_kernel<<<blocks, 256, 0, stream>>>(score, smax, dst, denom, E);
  }

  // Aggregate per destination node
  agg_kernel<<<N, 128, 0, stream>>>(v, score, denom, row_start, edge_list, src, out_pre, N);

  // Output projection
  {
    dim3 grid(rowTiles, 2);
    gemm_f32_128<<<grid, 256, 0, stream>>>(out_pre, Wo, bo, out, N);
  }
}

// Round 2
// 509.321 us; speedup vs baseline: 1.4883x; 1.4883x over previous
//
#include <hip/hip_runtime.h>
#include <hip/hip_bf16.h>

// N=50000, E=800000, D=128, H=8, HD=16, ED=16

#define DMODEL 128
#define NHEAD 8
#define HDIM 16
#define EDIM 16

// ---------------------------------------------------------------------------
// Tiled fp32 GEMM: C[M,128] = A[M,128] @ B[128,128] + bias[128]
// 64x64 tile, 256 threads, full K=128 staged in LDS.
// ---------------------------------------------------------------------------
__global__ __launch_bounds__(256) void gemm_f32_128(
    const float* __restrict__ A, const float* __restrict__ B,
    const float* __restrict__ bias, float* __restrict__ C, int M) {
  __shared__ float As[64][132];
  __shared__ float Bs[128][64];

  const int row0 = blockIdx.x * 64;
  const int col0 = blockIdx.y * 64;
  const int tid = threadIdx.x;

  #pragma unroll
  for (int i = 0; i < 8; ++i) {
    int idx = tid + i * 256;
    int r = idx >> 5;
    int c4 = idx & 31;
    int gr = row0 + r;
    float4 vv = make_float4(0.f, 0.f, 0.f, 0.f);
    if (gr < M) vv = *(const float4*)(A + (size_t)gr * DMODEL + c4 * 4);
    *(float4*)&As[r][c4 * 4] = vv;
  }
  #pragma unroll
  for (int i = 0; i < 8; ++i) {
    int idx = tid + i * 256;
    int r = idx >> 4;
    int c4 = idx & 15;
    *(float4*)&Bs[r][c4 * 4] = *(const float4*)(B + (size_t)r * DMODEL + col0 + c4 * 4);
  }
  __syncthreads();

  const int ty = tid >> 4;
  const int tx = tid & 15;
  float acc[4][4] = {};

  #pragma unroll 4
  for (int k = 0; k < 128; ++k) {
    float a0 = As[ty * 4 + 0][k];
    float a1 = As[ty * 4 + 1][k];
    float a2 = As[ty * 4 + 2][k];
    float a3 = As[ty * 4 + 3][k];
    float4 b = *(float4*)&Bs[k][tx * 4];
    acc[0][0] += a0 * b.x; acc[0][1] += a0 * b.y; acc[0][2] += a0 * b.z; acc[0][3] += a0 * b.w;
    acc[1][0] += a1 * b.x; acc[1][1] += a1 * b.y; acc[1][2] += a1 * b.z; acc[1][3] += a1 * b.w;
    acc[2][0] += a2 * b.x; acc[2][1] += a2 * b.y; acc[2][2] += a2 * b.z; acc[2][3] += a2 * b.w;
    acc[3][0] += a3 * b.x; acc[3][1] += a3 * b.y; acc[3][2] += a3 * b.z; acc[3][3] += a3 * b.w;
  }

  const int gc = col0 + tx * 4;
  float4 bs = *(const float4*)(bias + gc);
  #pragma unroll
  for (int i = 0; i < 4; ++i) {
    int gr = row0 + ty * 4 + i;
    if (gr < M) {
      float4 o;
      o.x = acc[i][0] + bs.x;
      o.y = acc[i][1] + bs.y;
      o.z = acc[i][2] + bs.z;
      o.w = acc[i][3] + bs.w;
      *(float4*)(C + (size_t)gr * DMODEL + gc) = o;
    }
  }
}

// ---------------------------------------------------------------------------
// CSR build: count, two-level scan, fill (writes src/eidx directly, no cursor)
// ---------------------------------------------------------------------------
__global__ void count_kernel(const int* __restrict__ dst, int* __restrict__ counts, int E) {
  int e = blockIdx.x * blockDim.x + threadIdx.x;
  if (e < E) atomicAdd(&counts[dst[e]], 1);
}

__global__ __launch_bounds__(1024) void scan1_kernel(const int* __restrict__ counts,
                                                     int* __restrict__ row_start,
                                                     int* __restrict__ partials, int n) {
  __shared__ int lds[1024];
  int i = blockIdx.x * 1024 + threadIdx.x;
  int val = (i < n) ? counts[i] : 0;
  lds[threadIdx.x] = val;
  __syncthreads();
  for (int off = 1; off < 1024; off <<= 1) {
    int tv = (threadIdx.x >= off) ? lds[threadIdx.x - off] : 0;
    __syncthreads();
    lds[threadIdx.x] += tv;
    __syncthreads();
  }
  if (i < n) row_start[i + 1] = lds[threadIdx.x];
  if (threadIdx.x == 1023) partials[blockIdx.x] = lds[1023];
  if (i == 0) row_start[0] = 0;
}

// single-wave inclusive scan of block partials (nb <= 64)
__global__ void scan2_kernel(int* __restrict__ partials, int nb) {
  int l = threadIdx.x;
  int v = (l < nb) ? partials[l] : 0;
  #pragma unroll
  for (int off = 1; off < 64; off <<= 1) {
    int t = __shfl_up(v, off, 64);
    if (l >= off) v += t;
  }
  if (l < nb) partials[l] = v;
}

__global__ __launch_bounds__(1024) void scan3_kernel(int* __restrict__ row_start,
                                                     const int* __restrict__ partials, int n) {
  if (blockIdx.x == 0) return;
  int i = blockIdx.x * 1024 + threadIdx.x;
  if (i < n) row_start[i + 1] += partials[blockIdx.x - 1];
}

__global__ void fill_kernel(const int* __restrict__ dst, const int* __restrict__ src,
                            const int* __restrict__ row_start, int* __restrict__ counts,
                            int* __restrict__ src_sorted, int* __restrict__ eidx_sorted, int E) {
  int e = blockIdx.x * blockDim.x + threadIdx.x;
  if (e < E) {
    int dn = dst[e];
    int p = atomicAdd(&counts[dn], -1) - 1;   // counts holds degree; unique slots [0, deg)
    int slot = row_start[dn] + p;
    src_sorted[slot] = src[e];
    eidx_sorted[slot] = e;
  }
}

// ---------------------------------------------------------------------------
// Fused flash-style per-node kernel: score + online softmax + weighted agg.
// One 128-thread block per dst node. Thread t owns feature dim t, head t>>4.
// score[e,h] = dot(k[src],q[n])_h * 0.25 + (e_feat[e] @ We)[h] + be[h]
// out_pre[n,t] = sum_e softmax_e(score)[h] * v[src_e, t]
// ---------------------------------------------------------------------------
__global__ __launch_bounds__(128) void fused_attn_kernel(
    const float* __restrict__ kmat, const float* __restrict__ qmat,
    const float* __restrict__ vmat, const float* __restrict__ e_feat,
    const float* __restrict__ We, const float* __restrict__ be,
    const int* __restrict__ row_start, const int* __restrict__ src_sorted,
    const int* __restrict__ eidx_sorted, float* __restrict__ out_pre, int N) {
  const int n = blockIdx.x;
  const int t = threadIdx.x;
  const int h = t >> 4;
  const int j = t & 15;

  const float qv   = qmat[(size_t)n * DMODEL + t];
  const float wcol = We[j * NHEAD + h];
  const float beh  = be[h];

  const int e0 = row_start[n];
  const int e1 = row_start[n + 1];

  float m = -INFINITY, d = 0.f, acc = 0.f;

  for (int i = e0; i < e1; ++i) {
    int s = src_sorted[i];
    int e = eidx_sorted[i];
    float kv = kmat[(size_t)s * DMODEL + t];
    float vv = vmat[(size_t)s * DMODEL + t];
    float ef = e_feat[(size_t)e * EDIM + j];
    float part = kv * qv * 0.25f + ef * wcol;   // HD^-0.5 = 0.25
    // reduce across the 16-lane head group
    #pragma unroll
    for (int off = 8; off >= 1; off >>= 1)
      part += __shfl_xor(part, off, 64);
    float sc = part + beh;
    // online softmax update
    float mnew = fmaxf(m, sc);
    float so = __expf(m - mnew);     // first iter: exp(-inf)=0
    float p  = __expf(sc - mnew);
    d   = d * so + p;
    acc = acc * so + p * vv;
    m = mnew;
  }

  float rd = (d > 0.f) ? 1.0f / d : 0.f;   // degree-0 node -> zeros (matches segment_sum)
  out_pre[(size_t)n * DMODEL + t] = acc * rd;
}

// ---------------------------------------------------------------------------
// Launch
// ---------------------------------------------------------------------------
extern "C" void kernel_launch(void* const* d_in, const int* in_sizes, int n_in,
                              void* d_out, int out_size, void* d_ws, size_t ws_size,
                              hipStream_t stream) {
  const float* h_in  = (const float*)d_in[0];
  const int*   src   = (const int*)d_in[1];
  const int*   dst   = (const int*)d_in[2];
  const float* e_feat= (const float*)d_in[3];
  const float* Wq    = (const float*)d_in[4];
  const float* bq    = (const float*)d_in[5];
  const float* Wk    = (const float*)d_in[6];
  const float* bk    = (const float*)d_in[7];
  const float* Wv    = (const float*)d_in[8];
  const float* bv    = (const float*)d_in[9];
  const float* We    = (const float*)d_in[10];
  const float* be    = (const float*)d_in[11];
  const float* Wo    = (const float*)d_in[12];
  const float* bo    = (const float*)d_in[13];
  float* out = (float*)d_out;

  const int N = in_sizes[0] / DMODEL;
  const int E = in_sizes[1];

  char* ws = (char*)d_ws;
  size_t off = 0;
  auto alloc = [&](size_t bytes) {
    size_t o = off;
    off = (off + bytes + 255) & ~(size_t)255;
    return o;
  };
  float* q          = (float*)(ws + alloc((size_t)N * DMODEL * 4));
  float* k          = (float*)(ws + alloc((size_t)N * DMODEL * 4));
  float* v          = (float*)(ws + alloc((size_t)N * DMODEL * 4));
  int*   counts     = (int*)(ws + alloc((size_t)N * 4));
  int*   row_start  = (int*)(ws + alloc((size_t)(N + 1) * 4));
  int*   partials   = (int*)(ws + alloc((size_t)64 * 4));
  int*   src_sorted = (int*)(ws + alloc((size_t)E * 4));
  int*   eidx_sorted= (int*)(ws + alloc((size_t)E * 4));
  float* out_pre    = (float*)(ws + alloc((size_t)N * DMODEL * 4));
  (void)ws_size;

  hipMemsetAsync(counts, 0, (size_t)N * 4, stream);

  const int rowTiles = (N + 63) / 64;
  const int scanBlocks = (N + 1023) / 1024;   // 49 <= 64

  // QKV projections
  {
    dim3 grid(rowTiles, 2);
    gemm_f32_128<<<grid, 256, 0, stream>>>(h_in, Wq, bq, q, N);
    gemm_f32_128<<<grid, 256, 0, stream>>>(h_in, Wk, bk, k, N);
    gemm_f32_128<<<grid, 256, 0, stream>>>(h_in, Wv, bv, v, N);
  }

  // CSR build
  {
    int blocks = (E + 255) / 256;
    count_kernel<<<blocks, 256, 0, stream>>>(dst, counts, E);
    scan1_kernel<<<scanBlocks, 1024, 0, stream>>>(counts, row_start, partials, N);
    scan2_kernel<<<1, 64, 0, stream>>>(partials, scanBlocks);
    scan3_kernel<<<scanBlocks, 1024, 0, stream>>>(row_start, partials, N);
    fill_kernel<<<blocks, 256, 0, stream>>>(dst, src, row_start, counts,
                                            src_sorted, eidx_sorted, E);
  }

  // Fused score + softmax + aggregate
  fused_attn_kernel<<<N, 128, 0, stream>>>(k, q, v, e_feat, We, be,
                                           row_start, src_sorted, eidx_sorted, out_pre, N);

  // Output projection
  {
    dim3 grid(rowTiles, 2);
    gemm_f32_128<<<grid, 256, 0, stream>>>(out_pre, Wo, bo, out, N);
  }
}

// Round 4
// 481.702 us; speedup vs baseline: 1.5737x; 1.0573x over previous
//
#include <hip/hip_runtime.h>
#include <hip/hip_bf16.h>
#include <type_traits>

// N=50000, E=800000, D=128, H=8, HD=16, ED=16

#define DMODEL 128
#define NHEAD 8
#define HDIM 16
#define EDIM 16

// ---------------------------------------------------------------------------
// Tiled fp32 GEMM: C[M,128] = (A[M,128] @ B[128,128] + bias[128]) * oscale
// 64x64 tile, 256 threads, full K=128 staged in LDS.
// k-chunked by 4 so both A and B fragments are ds_read_b128.
// OutT = float or __hip_bfloat16.
// ---------------------------------------------------------------------------
template <typename OutT>
__global__ __launch_bounds__(256) void gemm_f32_128(
    const float* __restrict__ A, const float* __restrict__ B,
    const float* __restrict__ bias, OutT* __restrict__ C, int M, float oscale) {
  __shared__ float As[64][132];   // pad: 132 mod 32 = 4 -> 2-way (free)
  __shared__ float Bs[128][64];

  const int row0 = blockIdx.x * 64;
  const int col0 = blockIdx.y * 64;
  const int tid = threadIdx.x;

  #pragma unroll
  for (int i = 0; i < 8; ++i) {
    int idx = tid + i * 256;
    int r = idx >> 5;
    int c4 = idx & 31;
    int gr = row0 + r;
    float4 vv = make_float4(0.f, 0.f, 0.f, 0.f);
    if (gr < M) vv = *(const float4*)(A + (size_t)gr * DMODEL + c4 * 4);
    *(float4*)&As[r][c4 * 4] = vv;
  }
  #pragma unroll
  for (int i = 0; i < 8; ++i) {
    int idx = tid + i * 256;
    int r = idx >> 4;
    int c4 = idx & 15;
    *(float4*)&Bs[r][c4 * 4] = *(const float4*)(B + (size_t)r * DMODEL + col0 + c4 * 4);
  }
  __syncthreads();

  const int ty = tid >> 4;
  const int tx = tid & 15;
  float acc[4][4] = {};

  #pragma unroll 2
  for (int k4 = 0; k4 < 32; ++k4) {
    float4 av[4], bv[4];
    #pragma unroll
    for (int i = 0; i < 4; ++i) av[i] = *(float4*)&As[ty * 4 + i][k4 * 4];
    #pragma unroll
    for (int i = 0; i < 4; ++i) bv[i] = *(float4*)&Bs[k4 * 4 + i][tx * 4];
    #pragma unroll
    for (int r = 0; r < 4; ++r) {
      const float* ar = (const float*)&av[r];
      #pragma unroll
      for (int kk = 0; kk < 4; ++kk) {
        const float* bk = (const float*)&bv[kk];
        acc[r][0] += ar[kk] * bk[0];
        acc[r][1] += ar[kk] * bk[1];
        acc[r][2] += ar[kk] * bk[2];
        acc[r][3] += ar[kk] * bk[3];
      }
    }
  }

  const int gc = col0 + tx * 4;
  float4 bs = *(const float4*)(bias + gc);
  #pragma unroll
  for (int r = 0; r < 4; ++r) {
    int gr = row0 + ty * 4 + r;
    if (gr < M) {
      float o0 = (acc[r][0] + bs.x) * oscale;
      float o1 = (acc[r][1] + bs.y) * oscale;
      float o2 = (acc[r][2] + bs.z) * oscale;
      float o3 = (acc[r][3] + bs.w) * oscale;
      if constexpr (std::is_same_v<OutT, float>) {
        float4 o = make_float4(o0, o1, o2, o3);
        *(float4*)(C + (size_t)gr * DMODEL + gc) = o;
      } else {
        union { ushort4 u; __hip_bfloat16 b[4]; } pk;
        pk.b[0] = __float2bfloat16(o0);
        pk.b[1] = __float2bfloat16(o1);
        pk.b[2] = __float2bfloat16(o2);
        pk.b[3] = __float2bfloat16(o3);
        *(ushort4*)(C + (size_t)gr * DMODEL + gc) = pk.u;
      }
    }
  }
}

// ---------------------------------------------------------------------------
// CSR build: count, two-level scan, fill (fill also computes sorted edge bias)
// ---------------------------------------------------------------------------
__global__ void count_kernel(const int* __restrict__ dst, int* __restrict__ counts, int E) {
  int e = blockIdx.x * blockDim.x + threadIdx.x;
  if (e < E) atomicAdd(&counts[dst[e]], 1);
}

__global__ __launch_bounds__(1024) void scan1_kernel(const int* __restrict__ counts,
                                                     int* __restrict__ row_start,
                                                     int* __restrict__ partials, int n) {
  __shared__ int lds[1024];
  int i = blockIdx.x * 1024 + threadIdx.x;
  int val = (i < n) ? counts[i] : 0;
  lds[threadIdx.x] = val;
  __syncthreads();
  for (int off = 1; off < 1024; off <<= 1) {
    int tv = (threadIdx.x >= off) ? lds[threadIdx.x - off] : 0;
    __syncthreads();
    lds[threadIdx.x] += tv;
    __syncthreads();
  }
  if (i < n) row_start[i + 1] = lds[threadIdx.x];
  if (threadIdx.x == 1023) partials[blockIdx.x] = lds[1023];
  if (i == 0) row_start[0] = 0;
}

__global__ void scan2_kernel(int* __restrict__ partials, int nb) {
  int l = threadIdx.x;
  int v = (l < nb) ? partials[l] : 0;
  #pragma unroll
  for (int off = 1; off < 64; off <<= 1) {
    int t = __shfl_up(v, off, 64);
    if (l >= off) v += t;
  }
  if (l < nb) partials[l] = v;
}

__global__ __launch_bounds__(1024) void scan3_kernel(int* __restrict__ row_start,
                                                     const int* __restrict__ partials, int n) {
  if (blockIdx.x == 0) return;
  int i = blockIdx.x * 1024 + threadIdx.x;
  if (i < n) row_start[i + 1] += partials[blockIdx.x - 1];
}

// fill: place edge into its dst bucket; write src_sorted and the full edge
// bias (e_feat @ We + be) into bias_sorted[slot*8 + h].
__global__ __launch_bounds__(256) void fill_kernel(
    const int* __restrict__ dst, const int* __restrict__ src,
    const float* __restrict__ e_feat, const float* __restrict__ We,
    const float* __restrict__ be, const int* __restrict__ row_start,
    int* __restrict__ counts, int* __restrict__ src_sorted,
    float* __restrict__ bias_sorted, int E) {
  int e = blockIdx.x * blockDim.x + threadIdx.x;
  if (e >= E) return;
  int dn = dst[e];
  int p = atomicAdd(&counts[dn], -1) - 1;
  int slot = row_start[dn] + p;
  src_sorted[slot] = src[e];

  float4 b03 = *(const float4*)(be);
  float4 b47 = *(const float4*)(be + 4);
  float bias[8] = {b03.x, b03.y, b03.z, b03.w, b47.x, b47.y, b47.z, b47.w};

  float4 ef[4];
  #pragma unroll
  for (int i = 0; i < 4; ++i) ef[i] = *(const float4*)(e_feat + (size_t)e * EDIM + i * 4);
  const float* efp = (const float*)ef;
  #pragma unroll
  for (int j = 0; j < 16; ++j) {
    float4 w0 = *(const float4*)(We + j * NHEAD);
    float4 w1 = *(const float4*)(We + j * NHEAD + 4);
    float efj = efp[j];
    bias[0] += efj * w0.x; bias[1] += efj * w0.y;
    bias[2] += efj * w0.z; bias[3] += efj * w0.w;
    bias[4] += efj * w1.x; bias[5] += efj * w1.y;
    bias[6] += efj * w1.z; bias[7] += efj * w1.w;
  }
  *(float4*)(bias_sorted + (size_t)slot * 8)     = make_float4(bias[0], bias[1], bias[2], bias[3]);
  *(float4*)(bias_sorted + (size_t)slot * 8 + 4) = make_float4(bias[4], bias[5], bias[6], bias[7]);
}

// ---------------------------------------------------------------------------
// Fused flash-style per-node kernel. One 128-thread block per dst node.
// Thread t owns feature dim t, head h=t>>4. k has 0.25 scale pre-folded.
// ---------------------------------------------------------------------------
__global__ __launch_bounds__(128) void fused_attn_kernel(
    const __hip_bfloat16* __restrict__ kmat, const float* __restrict__ qmat,
    const __hip_bfloat16* __restrict__ vmat, const float* __restrict__ bias_sorted,
    const int* __restrict__ row_start, const int* __restrict__ src_sorted,
    float* __restrict__ out_pre, int N) {
  const int n = blockIdx.x;
  const int t = threadIdx.x;
  const int h = t >> 4;

  const float qv = qmat[(size_t)n * DMODEL + t];
  const int e0 = row_start[n];
  const int e1 = row_start[n + 1];

  float m = -INFINITY, d = 0.f, acc = 0.f;

  for (int i = e0; i < e1; ++i) {
    int s = src_sorted[i];
    float kv = __bfloat162float(kmat[(size_t)s * DMODEL + t]);
    float vv = __bfloat162float(vmat[(size_t)s * DMODEL + t]);
    float bias = bias_sorted[(size_t)i * 8 + h];
    float part = kv * qv;
    #pragma unroll
    for (int off = 8; off >= 1; off >>= 1)
      part += __shfl_xor(part, off, 64);
    float sc = part + bias;
    float mnew = fmaxf(m, sc);
    float so = __expf(m - mnew);
    float p  = __expf(sc - mnew);
    d   = d * so + p;
    acc = acc * so + p * vv;
    m = mnew;
  }

  float rd = (d > 0.f) ? 1.0f / d : 0.f;
  out_pre[(size_t)n * DMODEL + t] = acc * rd;
}

// ---------------------------------------------------------------------------
// Launch
// ---------------------------------------------------------------------------
extern "C" void kernel_launch(void* const* d_in, const int* in_sizes, int n_in,
                              void* d_out, int out_size, void* d_ws, size_t ws_size,
                              hipStream_t stream) {
  const float* h_in  = (const float*)d_in[0];
  const int*   src   = (const int*)d_in[1];
  const int*   dst   = (const int*)d_in[2];
  const float* e_feat= (const float*)d_in[3];
  const float* Wq    = (const float*)d_in[4];
  const float* bq    = (const float*)d_in[5];
  const float* Wk    = (const float*)d_in[6];
  const float* bk    = (const float*)d_in[7];
  const float* Wv    = (const float*)d_in[8];
  const float* bv    = (const float*)d_in[9];
  const float* We    = (const float*)d_in[10];
  const float* be    = (const float*)d_in[11];
  const float* Wo    = (const float*)d_in[12];
  const float* bo    = (const float*)d_in[13];
  float* out = (float*)d_out;

  const int N = in_sizes[0] / DMODEL;
  const int E = in_sizes[1];

  char* ws = (char*)d_ws;
  size_t off = 0;
  auto alloc = [&](size_t bytes) {
    size_t o = off;
    off = (off + bytes + 255) & ~(size_t)255;
    return o;
  };
  float*           q          = (float*)(ws + alloc((size_t)N * DMODEL * 4));
  __hip_bfloat16*  k          = (__hip_bfloat16*)(ws + alloc((size_t)N * DMODEL * 2));
  __hip_bfloat16*  v          = (__hip_bfloat16*)(ws + alloc((size_t)N * DMODEL * 2));
  int*             counts     = (int*)(ws + alloc((size_t)N * 4));
  int*             row_start  = (int*)(ws + alloc((size_t)(N + 1) * 4));
  int*             partials   = (int*)(ws + alloc((size_t)64 * 4));
  int*             src_sorted = (int*)(ws + alloc((size_t)E * 4));
  float*           bias_sorted= (float*)(ws + alloc((size_t)E * NHEAD * 4));
  float*           out_pre    = (float*)(ws + alloc((size_t)N * DMODEL * 4));
  (void)ws_size;

  hipMemsetAsync(counts, 0, (size_t)N * 4, stream);

  const int rowTiles = (N + 63) / 64;
  const int scanBlocks = (N + 1023) / 1024;

  // QKV projections (k gets the 0.25 attention scale folded in; exact in bf16)
  {
    dim3 grid(rowTiles, 2);
    gemm_f32_128<float><<<grid, 256, 0, stream>>>(h_in, Wq, bq, q, N, 1.0f);
    gemm_f32_128<__hip_bfloat16><<<grid, 256, 0, stream>>>(h_in, Wk, bk, k, N, 0.25f);
    gemm_f32_128<__hip_bfloat16><<<grid, 256, 0, stream>>>(h_in, Wv, bv, v, N, 1.0f);
  }

  // CSR build + sorted edge bias
  {
    int blocks = (E + 255) / 256;
    count_kernel<<<blocks, 256, 0, stream>>>(dst, counts, E);
    scan1_kernel<<<scanBlocks, 1024, 0, stream>>>(counts, row_start, partials, N);
    scan2_kernel<<<1, 64, 0, stream>>>(partials, scanBlocks);
    scan3_kernel<<<scanBlocks, 1024, 0, stream>>>(row_start, partials, N);
    fill_kernel<<<blocks, 256, 0, stream>>>(dst, src, e_feat, We, be, row_start,
                                            counts, src_sorted, bias_sorted, E);
  }

  // Fused score + softmax + aggregate
  fused_attn_kernel<<<N, 128, 0, stream>>>(k, q, v, bias_sorted,
                                           row_start, src_sorted, out_pre, N);

  // Output projection
  {
    dim3 grid(rowTiles, 2);
    gemm_f32_128<float><<<grid, 256, 0, stream>>>(out_pre, Wo, bo, out, N, 1.0f);
  }
}

// Round 5
// 411.749 us; speedup vs baseline: 1.8410x; 1.1699x over previous
//
#include <hip/hip_runtime.h>
#include <hip/hip_bf16.h>
#include <type_traits>

// N=50000, E=800000, D=128, H=8, HD=16, ED=16

#define DMODEL 128
#define NHEAD 8
#define EDIM 16

typedef __attribute__((ext_vector_type(8))) short short8v;
typedef __attribute__((ext_vector_type(4))) float float4v;

__device__ __forceinline__ unsigned short f2bf(float x) {
  union { __hip_bfloat16 b; unsigned short u; } c;
  c.b = __float2bfloat16(x);
  return c.u;
}
__device__ __forceinline__ float bfbits2f(unsigned short u) {
  return __uint_as_float(((unsigned)u) << 16);
}

// ---------------------------------------------------------------------------
// Pack the four 128x128 weight matrices into MFMA B-fragment order, split
// into bf16 hi/lo. Layout per weight w (32768 ushorts):
//   hi[idx] at w*32768 + idx, lo[idx] at w*32768 + 16384 + idx
//   idx = ((ct*4 + ks)*64 + lane)*8 + j
//   element = W[ks*32 + (lane>>4)*8 + j][ct*16 + (lane&15)]
// ---------------------------------------------------------------------------
__global__ __launch_bounds__(256) void pack_w_kernel(
    const float* __restrict__ W0, const float* __restrict__ W1,
    const float* __restrict__ W2, const float* __restrict__ W3,
    unsigned short* __restrict__ wpack) {
  int g = blockIdx.x * 256 + threadIdx.x;    // 65536 total
  int w = g >> 14;
  int idx = g & 16383;
  int j = idx & 7;
  int lane = (idx >> 3) & 63;
  int ks = (idx >> 9) & 3;
  int ct = idx >> 11;
  int k = ks * 32 + ((lane >> 4) << 3) + j;
  int col = ct * 16 + (lane & 15);
  const float* W = (w == 0) ? W0 : (w == 1) ? W1 : (w == 2) ? W2 : W3;
  float x = W[k * DMODEL + col];
  unsigned short hi = f2bf(x);
  unsigned short lo = f2bf(x - bfbits2f(hi));
  wpack[(size_t)w * 32768 + idx] = hi;
  wpack[(size_t)w * 32768 + 16384 + idx] = lo;
}

// ---------------------------------------------------------------------------
// MFMA GEMM: C[M,128] = (A[M,128] @ W + bias) * oscale, fp32 A, split-bf16 W.
// 256 threads = 4 waves; block covers 64 rows, wave -> 16 rows.
// Per wave: 8 col-tiles x 4 k-steps x 3 MFMA (hihi + hilo + lohi).
// mfma_f32_16x16x32_bf16 layouts (m89-verified C/D):
//   A: lane l -> row l&15,  k = (l>>4)*8 + j
//   B: lane l -> col l&15,  k = (l>>4)*8 + j   (packed contiguously by pack_w)
//   D: lane l -> col l&15, row = (l>>4)*4 + reg
// ---------------------------------------------------------------------------
template <typename OutT>
__global__ __launch_bounds__(256) void mfma_gemm_128(
    const float* __restrict__ A, const unsigned short* __restrict__ wpk,
    const float* __restrict__ bias, OutT* __restrict__ C, int M, float oscale) {
  const int wv = threadIdx.x >> 6;
  const int l  = threadIdx.x & 63;
  const int row0 = blockIdx.x * 64 + wv * 16;
  const int arow = min(row0 + (l & 15), M - 1);
  const int kofs = (l >> 4) * 8;

  // A fragments for all 4 k-steps, converted to bf16 hi/lo in registers
  short8v ahi[4], alo[4];
  #pragma unroll
  for (int ks = 0; ks < 4; ++ks) {
    const float* ap = A + (size_t)arow * DMODEL + ks * 32 + kofs;
    float4 f0 = *(const float4*)ap;
    float4 f1 = *(const float4*)(ap + 4);
    float xs[8] = {f0.x, f0.y, f0.z, f0.w, f1.x, f1.y, f1.z, f1.w};
    #pragma unroll
    for (int j = 0; j < 8; ++j) {
      unsigned short h = f2bf(xs[j]);
      ahi[ks][j] = (short)h;
      alo[ks][j] = (short)f2bf(xs[j] - bfbits2f(h));
    }
  }

  #pragma unroll
  for (int ct = 0; ct < 8; ++ct) {
    float4v acc = {0.f, 0.f, 0.f, 0.f};
    #pragma unroll
    for (int ks = 0; ks < 4; ++ks) {
      const unsigned short* bp = wpk + ((size_t)(ct * 4 + ks) * 64 + l) * 8;
      short8v bhi = *(const short8v*)bp;
      short8v blo = *(const short8v*)(bp + 16384);
      acc = __builtin_amdgcn_mfma_f32_16x16x32_bf16(ahi[ks], bhi, acc, 0, 0, 0);
      acc = __builtin_amdgcn_mfma_f32_16x16x32_bf16(ahi[ks], blo, acc, 0, 0, 0);
      acc = __builtin_amdgcn_mfma_f32_16x16x32_bf16(alo[ks], bhi, acc, 0, 0, 0);
    }
    const int col = ct * 16 + (l & 15);
    const float bs = bias[col];
    #pragma unroll
    for (int j = 0; j < 4; ++j) {
      int r = row0 + (l >> 4) * 4 + j;
      if (r < M) {
        float o = (acc[j] + bs) * oscale;
        if constexpr (std::is_same_v<OutT, float>) {
          C[(size_t)r * DMODEL + col] = o;
        } else {
          C[(size_t)r * DMODEL + col] = __float2bfloat16(o);
        }
      }
    }
  }
}

// ---------------------------------------------------------------------------
// CSR build: count, two-level scan, fill (fill also computes sorted edge bias)
// ---------------------------------------------------------------------------
__global__ void count_kernel(const int* __restrict__ dst, int* __restrict__ counts, int E) {
  int e = blockIdx.x * blockDim.x + threadIdx.x;
  if (e < E) atomicAdd(&counts[dst[e]], 1);
}

__global__ __launch_bounds__(1024) void scan1_kernel(const int* __restrict__ counts,
                                                     int* __restrict__ row_start,
                                                     int* __restrict__ partials, int n) {
  __shared__ int lds[1024];
  int i = blockIdx.x * 1024 + threadIdx.x;
  int val = (i < n) ? counts[i] : 0;
  lds[threadIdx.x] = val;
  __syncthreads();
  for (int off = 1; off < 1024; off <<= 1) {
    int tv = (threadIdx.x >= off) ? lds[threadIdx.x - off] : 0;
    __syncthreads();
    lds[threadIdx.x] += tv;
    __syncthreads();
  }
  if (i < n) row_start[i + 1] = lds[threadIdx.x];
  if (threadIdx.x == 1023) partials[blockIdx.x] = lds[1023];
  if (i == 0) row_start[0] = 0;
}

__global__ void scan2_kernel(int* __restrict__ partials, int nb) {
  int l = threadIdx.x;
  int v = (l < nb) ? partials[l] : 0;
  #pragma unroll
  for (int off = 1; off < 64; off <<= 1) {
    int t = __shfl_up(v, off, 64);
    if (l >= off) v += t;
  }
  if (l < nb) partials[l] = v;
}

__global__ __launch_bounds__(1024) void scan3_kernel(int* __restrict__ row_start,
                                                     const int* __restrict__ partials, int n) {
  if (blockIdx.x == 0) return;
  int i = blockIdx.x * 1024 + threadIdx.x;
  if (i < n) row_start[i + 1] += partials[blockIdx.x - 1];
}

__global__ __launch_bounds__(256) void fill_kernel(
    const int* __restrict__ dst, const int* __restrict__ src,
    const float* __restrict__ e_feat, const float* __restrict__ We,
    const float* __restrict__ be, const int* __restrict__ row_start,
    int* __restrict__ counts, int* __restrict__ src_sorted,
    float* __restrict__ bias_sorted, int E) {
  int e = blockIdx.x * blockDim.x + threadIdx.x;
  if (e >= E) return;
  int dn = dst[e];
  int p = atomicAdd(&counts[dn], -1) - 1;
  int slot = row_start[dn] + p;
  src_sorted[slot] = src[e];

  float4 b03 = *(const float4*)(be);
  float4 b47 = *(const float4*)(be + 4);
  float bias[8] = {b03.x, b03.y, b03.z, b03.w, b47.x, b47.y, b47.z, b47.w};

  float4 ef[4];
  #pragma unroll
  for (int i = 0; i < 4; ++i) ef[i] = *(const float4*)(e_feat + (size_t)e * EDIM + i * 4);
  const float* efp = (const float*)ef;
  #pragma unroll
  for (int j = 0; j < 16; ++j) {
    float4 w0 = *(const float4*)(We + j * NHEAD);
    float4 w1 = *(const float4*)(We + j * NHEAD + 4);
    float efj = efp[j];
    bias[0] += efj * w0.x; bias[1] += efj * w0.y;
    bias[2] += efj * w0.z; bias[3] += efj * w0.w;
    bias[4] += efj * w1.x; bias[5] += efj * w1.y;
    bias[6] += efj * w1.z; bias[7] += efj * w1.w;
  }
  *(float4*)(bias_sorted + (size_t)slot * 8)     = make_float4(bias[0], bias[1], bias[2], bias[3]);
  *(float4*)(bias_sorted + (size_t)slot * 8 + 4) = make_float4(bias[4], bias[5], bias[6], bias[7]);
}

// ---------------------------------------------------------------------------
// Fused flash-style attention, one WAVE per dst node (4 nodes / 256-block).
// Lane l owns dims 2l, 2l+1 (bf16x2 packed loads); head h = l>>3 (8 lanes).
// Defer-max online softmax (T13): rescale only when sc > m + 8.
// ---------------------------------------------------------------------------
__global__ __launch_bounds__(256) void fused_attn_kernel(
    const __hip_bfloat16* __restrict__ kmat, const float* __restrict__ qmat,
    const __hip_bfloat16* __restrict__ vmat, const float* __restrict__ bias_sorted,
    const int* __restrict__ row_start, const int* __restrict__ src_sorted,
    float* __restrict__ out_pre, int N) {
  const int node = blockIdx.x * 4 + (threadIdx.x >> 6);
  if (node >= N) return;
  const int l = threadIdx.x & 63;
  const int h = l >> 3;

  const float2 qv = *(const float2*)(qmat + (size_t)node * DMODEL + l * 2);
  const int e0 = row_start[node];
  const int e1 = row_start[node + 1];

  float m = -INFINITY, d = 0.f;
  float accx = 0.f, accy = 0.f;

  for (int i = e0; i < e1; ++i) {
    int s = src_sorted[i];
    unsigned kraw = *(const unsigned*)(kmat + (size_t)s * DMODEL + l * 2);
    unsigned vraw = *(const unsigned*)(vmat + (size_t)s * DMODEL + l * 2);
    float kx = __uint_as_float(kraw << 16);
    float ky = __uint_as_float(kraw & 0xffff0000u);
    float vx = __uint_as_float(vraw << 16);
    float vy = __uint_as_float(vraw & 0xffff0000u);

    float part = kx * qv.x + ky * qv.y;
    part += __shfl_xor(part, 1, 64);
    part += __shfl_xor(part, 2, 64);
    part += __shfl_xor(part, 4, 64);
    float sc = part + bias_sorted[(size_t)i * 8 + h];

    if (sc > m + 8.f) {                 // rare after warmup; first iter: exp(-inf)=0
      float f = __expf(m - sc);
      d *= f; accx *= f; accy *= f;
      m = sc;
    }
    float p = __expf(sc - m);           // bounded by e^8
    d += p;
    accx += p * vx;
    accy += p * vy;
  }

  float rd = (d > 0.f) ? 1.0f / d : 0.f;
  *(float2*)(out_pre + (size_t)node * DMODEL + l * 2) = make_float2(accx * rd, accy * rd);
}

// ---------------------------------------------------------------------------
// Launch
// ---------------------------------------------------------------------------
extern "C" void kernel_launch(void* const* d_in, const int* in_sizes, int n_in,
                              void* d_out, int out_size, void* d_ws, size_t ws_size,
                              hipStream_t stream) {
  const float* h_in  = (const float*)d_in[0];
  const int*   src   = (const int*)d_in[1];
  const int*   dst   = (const int*)d_in[2];
  const float* e_feat= (const float*)d_in[3];
  const float* Wq    = (const float*)d_in[4];
  const float* bq    = (const float*)d_in[5];
  const float* Wk    = (const float*)d_in[6];
  const float* bk    = (const float*)d_in[7];
  const float* Wv    = (const float*)d_in[8];
  const float* bv    = (const float*)d_in[9];
  const float* We    = (const float*)d_in[10];
  const float* be    = (const float*)d_in[11];
  const float* Wo    = (const float*)d_in[12];
  const float* bo    = (const float*)d_in[13];
  float* out = (float*)d_out;

  const int N = in_sizes[0] / DMODEL;
  const int E = in_sizes[1];

  char* ws = (char*)d_ws;
  size_t off = 0;
  auto alloc = [&](size_t bytes) {
    size_t o = off;
    off = (off + bytes + 255) & ~(size_t)255;
    return o;
  };
  float*           q          = (float*)(ws + alloc((size_t)N * DMODEL * 4));
  __hip_bfloat16*  k          = (__hip_bfloat16*)(ws + alloc((size_t)N * DMODEL * 2));
  __hip_bfloat16*  v          = (__hip_bfloat16*)(ws + alloc((size_t)N * DMODEL * 2));
  int*             counts     = (int*)(ws + alloc((size_t)N * 4));
  int*             row_start  = (int*)(ws + alloc((size_t)(N + 1) * 4));
  int*             partials   = (int*)(ws + alloc((size_t)64 * 4));
  int*             src_sorted = (int*)(ws + alloc((size_t)E * 4));
  float*           bias_sorted= (float*)(ws + alloc((size_t)E * NHEAD * 4));
  float*           out_pre    = (float*)(ws + alloc((size_t)N * DMODEL * 4));
  unsigned short*  wpack      = (unsigned short*)(ws + alloc((size_t)4 * 32768 * 2));
  (void)ws_size;

  hipMemsetAsync(counts, 0, (size_t)N * 4, stream);

  const int gemmBlocks = (N + 63) / 64;
  const int scanBlocks = (N + 1023) / 1024;

  // Pack all four weights into MFMA fragment order (hi/lo split)
  pack_w_kernel<<<256, 256, 0, stream>>>(Wq, Wk, Wv, Wo, wpack);

  // QKV projections via MFMA (k gets the 0.25 scale folded; exact in bf16)
  mfma_gemm_128<float><<<gemmBlocks, 256, 0, stream>>>(
      h_in, wpack + 0 * 32768, bq, q, N, 1.0f);
  mfma_gemm_128<__hip_bfloat16><<<gemmBlocks, 256, 0, stream>>>(
      h_in, wpack + 1 * 32768, bk, k, N, 0.25f);
  mfma_gemm_128<__hip_bfloat16><<<gemmBlocks, 256, 0, stream>>>(
      h_in, wpack + 2 * 32768, bv, v, N, 1.0f);

  // CSR build + sorted edge bias
  {
    int blocks = (E + 255) / 256;
    count_kernel<<<blocks, 256, 0, stream>>>(dst, counts, E);
    scan1_kernel<<<scanBlocks, 1024, 0, stream>>>(counts, row_start, partials, N);
    scan2_kernel<<<1, 64, 0, stream>>>(partials, scanBlocks);
    scan3_kernel<<<scanBlocks, 1024, 0, stream>>>(row_start, partials, N);
    fill_kernel<<<blocks, 256, 0, stream>>>(dst, src, e_feat, We, be, row_start,
                                            counts, src_sorted, bias_sorted, E);
  }

  // Fused score + softmax + aggregate (one wave per node)
  fused_attn_kernel<<<(N + 3) / 4, 256, 0, stream>>>(
      k, q, v, bias_sorted, row_start, src_sorted, out_pre, N);

  // Output projection via MFMA
  mfma_gemm_128<float><<<gemmBlocks, 256, 0, stream>>>(
      out_pre, wpack + 3 * 32768, bo, out, N, 1.0f);
}

// Round 8
// 400.964 us; speedup vs baseline: 1.8906x; 1.0269x over previous
//
#include <hip/hip_runtime.h>
#include <hip/hip_bf16.h>
#include <type_traits>

// N=50000, E=800000, D=128, H=8, HD=16, ED=16

#define DMODEL 128
#define NHEAD 8
#define EDIM 16

typedef __attribute__((ext_vector_type(8))) short short8v;
typedef __attribute__((ext_vector_type(4))) float float4v;

__device__ __forceinline__ unsigned short f2bf(float x) {
  union { __hip_bfloat16 b; unsigned short u; } c;
  c.b = __float2bfloat16(x);
  return c.u;
}
__device__ __forceinline__ float bfbits2f(unsigned short u) {
  return __uint_as_float(((unsigned)u) << 16);
}

// ---------------------------------------------------------------------------
// Pack the four 128x128 weight matrices into MFMA B-fragment order, split
// into bf16 hi/lo. Layout per weight w (32768 ushorts):
//   hi[idx] at w*32768 + idx, lo[idx] at w*32768 + 16384 + idx
//   idx = ((ct*4 + ks)*64 + lane)*8 + j
//   element = W[ks*32 + (lane>>4)*8 + j][ct*16 + (lane&15)]
// ---------------------------------------------------------------------------
__global__ __launch_bounds__(256) void pack_w_kernel(
    const float* __restrict__ W0, const float* __restrict__ W1,
    const float* __restrict__ W2, const float* __restrict__ W3,
    unsigned short* __restrict__ wpack) {
  int g = blockIdx.x * 256 + threadIdx.x;    // 65536 total
  int w = g >> 14;
  int idx = g & 16383;
  int j = idx & 7;
  int lane = (idx >> 3) & 63;
  int ks = (idx >> 9) & 3;
  int ct = idx >> 11;
  int k = ks * 32 + ((lane >> 4) << 3) + j;
  int col = ct * 16 + (lane & 15);
  const float* W = (w == 0) ? W0 : (w == 1) ? W1 : (w == 2) ? W2 : W3;
  float x = W[k * DMODEL + col];
  unsigned short hi = f2bf(x);
  unsigned short lo = f2bf(x - bfbits2f(hi));
  wpack[(size_t)w * 32768 + idx] = hi;
  wpack[(size_t)w * 32768 + 16384 + idx] = lo;
}

// ---------------------------------------------------------------------------
// MFMA GEMM: C[M,128] = (A[M,128] @ W + bias) * oscale, fp32 A, split-bf16 W.
// 256 threads = 4 waves; block covers 64 rows, wave -> 16 rows.
// Per wave: 8 col-tiles x 4 k-steps x 3 MFMA (hihi + hilo + lohi).
// KV: 0 = plain [M,128] output (OutT float or bf16)
//     1 = k-slot of interleaved kv buffer (ushort base, row stride 256)
//     2 = v-slot of interleaved kv buffer
// Interleaved layout: row r, col c -> ushort r*256 + (c>>1)*4 + (c&1) + (KV==2?2:0)
// ---------------------------------------------------------------------------
template <typename OutT, int KV>
__global__ __launch_bounds__(256) void mfma_gemm_128(
    const float* __restrict__ A, const unsigned short* __restrict__ wpk,
    const float* __restrict__ bias, OutT* __restrict__ C, int M, float oscale) {
  const int wv = threadIdx.x >> 6;
  const int l  = threadIdx.x & 63;
  const int row0 = blockIdx.x * 64 + wv * 16;
  const int arow = min(row0 + (l & 15), M - 1);
  const int kofs = (l >> 4) * 8;

  short8v ahi[4], alo[4];
  #pragma unroll
  for (int ks = 0; ks < 4; ++ks) {
    const float* ap = A + (size_t)arow * DMODEL + ks * 32 + kofs;
    float4 f0 = *(const float4*)ap;
    float4 f1 = *(const float4*)(ap + 4);
    float xs[8] = {f0.x, f0.y, f0.z, f0.w, f1.x, f1.y, f1.z, f1.w};
    #pragma unroll
    for (int j = 0; j < 8; ++j) {
      unsigned short h = f2bf(xs[j]);
      ahi[ks][j] = (short)h;
      alo[ks][j] = (short)f2bf(xs[j] - bfbits2f(h));
    }
  }

  #pragma unroll
  for (int ct = 0; ct < 8; ++ct) {
    float4v acc = {0.f, 0.f, 0.f, 0.f};
    #pragma unroll
    for (int ks = 0; ks < 4; ++ks) {
      const unsigned short* bp = wpk + ((size_t)(ct * 4 + ks) * 64 + l) * 8;
      short8v bhi = *(const short8v*)bp;
      short8v blo = *(const short8v*)(bp + 16384);
      acc = __builtin_amdgcn_mfma_f32_16x16x32_bf16(ahi[ks], bhi, acc, 0, 0, 0);
      acc = __builtin_amdgcn_mfma_f32_16x16x32_bf16(ahi[ks], blo, acc, 0, 0, 0);
      acc = __builtin_amdgcn_mfma_f32_16x16x32_bf16(alo[ks], bhi, acc, 0, 0, 0);
    }
    const int col = ct * 16 + (l & 15);
    const float bs = bias[col];
    #pragma unroll
    for (int j = 0; j < 4; ++j) {
      int r = row0 + (l >> 4) * 4 + j;
      if (r < M) {
        float o = (acc[j] + bs) * oscale;
        if constexpr (KV == 0) {
          if constexpr (std::is_same_v<OutT, float>) {
            C[(size_t)r * DMODEL + col] = o;
          } else {
            C[(size_t)r * DMODEL + col] = __float2bfloat16(o);
          }
        } else {
          unsigned short* kvp = (unsigned short*)C;
          kvp[(size_t)r * 256 + ((col >> 1) << 2) + (col & 1) + (KV == 2 ? 2 : 0)] = f2bf(o);
        }
      }
    }
  }
}

// ---------------------------------------------------------------------------
// Edge bias, coalesced: bias_ed[e*8+h] = (e_feat[e] @ We)[h] + be[h]
// ---------------------------------------------------------------------------
__global__ __launch_bounds__(256) void ebias_kernel(
    const float* __restrict__ e_feat, const float* __restrict__ We,
    const float* __restrict__ be, float* __restrict__ bias_ed, int E) {
  int e = blockIdx.x * blockDim.x + threadIdx.x;
  if (e >= E) return;
  float4 b03 = *(const float4*)(be);
  float4 b47 = *(const float4*)(be + 4);
  float bias[8] = {b03.x, b03.y, b03.z, b03.w, b47.x, b47.y, b47.z, b47.w};
  float4 ef[4];
  #pragma unroll
  for (int i = 0; i < 4; ++i) ef[i] = *(const float4*)(e_feat + (size_t)e * EDIM + i * 4);
  const float* efp = (const float*)ef;
  #pragma unroll
  for (int j = 0; j < 16; ++j) {
    float4 w0 = *(const float4*)(We + j * NHEAD);
    float4 w1 = *(const float4*)(We + j * NHEAD + 4);
    float efj = efp[j];
    bias[0] += efj * w0.x; bias[1] += efj * w0.y;
    bias[2] += efj * w0.z; bias[3] += efj * w0.w;
    bias[4] += efj * w1.x; bias[5] += efj * w1.y;
    bias[6] += efj * w1.z; bias[7] += efj * w1.w;
  }
  *(float4*)(bias_ed + (size_t)e * 8)     = make_float4(bias[0], bias[1], bias[2], bias[3]);
  *(float4*)(bias_ed + (size_t)e * 8 + 4) = make_float4(bias[4], bias[5], bias[6], bias[7]);
}

// ---------------------------------------------------------------------------
// CSR build: count, two-level scan, fill (8B int2 scatter only)
// ---------------------------------------------------------------------------
__global__ void count_kernel(const int* __restrict__ dst, int* __restrict__ counts, int E) {
  int e = blockIdx.x * blockDim.x + threadIdx.x;
  if (e < E) atomicAdd(&counts[dst[e]], 1);
}

__global__ __launch_bounds__(1024) void scan1_kernel(const int* __restrict__ counts,
                                                     int* __restrict__ row_start,
                                                     int* __restrict__ partials, int n) {
  __shared__ int lds[1024];
  int i = blockIdx.x * 1024 + threadIdx.x;
  int val = (i < n) ? counts[i] : 0;
  lds[threadIdx.x] = val;
  __syncthreads();
  for (int off = 1; off < 1024; off <<= 1) {
    int tv = (threadIdx.x >= off) ? lds[threadIdx.x - off] : 0;
    __syncthreads();
    lds[threadIdx.x] += tv;
    __syncthreads();
  }
  if (i < n) row_start[i + 1] = lds[threadIdx.x];
  if (threadIdx.x == 1023) partials[blockIdx.x] = lds[1023];
  if (i == 0) row_start[0] = 0;
}

__global__ void scan2_kernel(int* __restrict__ partials, int nb) {
  int l = threadIdx.x;
  int v = (l < nb) ? partials[l] : 0;
  #pragma unroll
  for (int off = 1; off < 64; off <<= 1) {
    int t = __shfl_up(v, off, 64);
    if (l >= off) v += t;
  }
  if (l < nb) partials[l] = v;
}

__global__ __launch_bounds__(1024) void scan3_kernel(int* __restrict__ row_start,
                                                     const int* __restrict__ partials, int n) {
  if (blockIdx.x == 0) return;
  int i = blockIdx.x * 1024 + threadIdx.x;
  if (i < n) row_start[i + 1] += partials[blockIdx.x - 1];
}

__global__ __launch_bounds__(256) void fill_kernel(
    const int* __restrict__ dst, const int* __restrict__ src,
    const int* __restrict__ row_start, int* __restrict__ counts,
    int2* __restrict__ pair_sorted, int E) {
  int e = blockIdx.x * blockDim.x + threadIdx.x;
  if (e >= E) return;
  int dn = dst[e];
  int p = atomicAdd(&counts[dn], -1) - 1;
  pair_sorted[row_start[dn] + p] = make_int2(src[e], e);
}

// ---------------------------------------------------------------------------
// Fused flash-style attention, one WAVE per dst node (4 nodes / 256-block).
// Lane l owns dims 2l,2l+1 via ONE 8B load of the interleaved kv row; head
// h = l>>3. Defer-max online softmax (T13). Edge loop unrolled x2 for MLP.
// ---------------------------------------------------------------------------
__global__ __launch_bounds__(256) void fused_attn_kernel(
    const unsigned short* __restrict__ kvmat, const float* __restrict__ qmat,
    const float* __restrict__ bias_ed, const int* __restrict__ row_start,
    const int2* __restrict__ pair_sorted, float* __restrict__ out_pre, int N) {
  const int node = blockIdx.x * 4 + (threadIdx.x >> 6);
  if (node >= N) return;
  const int l = threadIdx.x & 63;
  const int h = l >> 3;

  const float2 qv = *(const float2*)(qmat + (size_t)node * DMODEL + l * 2);
  const int e0 = row_start[node];
  const int e1 = row_start[node + 1];

  float m = -INFINITY, d = 0.f;
  float accx = 0.f, accy = 0.f;

  int i = e0;
  for (; i + 2 <= e1; i += 2) {
    int2 p0 = pair_sorted[i];
    int2 p1 = pair_sorted[i + 1];
    uint2 kv0 = *(const uint2*)(kvmat + (size_t)p0.x * 256 + l * 4);
    uint2 kv1 = *(const uint2*)(kvmat + (size_t)p1.x * 256 + l * 4);
    float b0 = bias_ed[(size_t)p0.y * 8 + h];
    float b1 = bias_ed[(size_t)p1.y * 8 + h];

    // edge 0
    {
      float kx = __uint_as_float(kv0.x << 16);
      float ky = __uint_as_float(kv0.x & 0xffff0000u);
      float part = kx * qv.x + ky * qv.y;
      part += __shfl_xor(part, 1, 64);
      part += __shfl_xor(part, 2, 64);
      part += __shfl_xor(part, 4, 64);
      float sc = part + b0;
      if (sc > m + 8.f) {
        float f = __expf(m - sc);
        d *= f; accx *= f; accy *= f;
        m = sc;
      }
      float p = __expf(sc - m);
      d += p;
      accx += p * __uint_as_float(kv0.y << 16);
      accy += p * __uint_as_float(kv0.y & 0xffff0000u);
    }
    // edge 1
    {
      float kx = __uint_as_float(kv1.x << 16);
      float ky = __uint_as_float(kv1.x & 0xffff0000u);
      float part = kx * qv.x + ky * qv.y;
      part += __shfl_xor(part, 1, 64);
      part += __shfl_xor(part, 2, 64);
      part += __shfl_xor(part, 4, 64);
      float sc = part + b1;
      if (sc > m + 8.f) {
        float f = __expf(m - sc);
        d *= f; accx *= f; accy *= f;
        m = sc;
      }
      float p = __expf(sc - m);
      d += p;
      accx += p * __uint_as_float(kv1.y << 16);
      accy += p * __uint_as_float(kv1.y & 0xffff0000u);
    }
  }
  if (i < e1) {
    int2 p0 = pair_sorted[i];
    uint2 kv0 = *(const uint2*)(kvmat + (size_t)p0.x * 256 + l * 4);
    float b0 = bias_ed[(size_t)p0.y * 8 + h];
    float kx = __uint_as_float(kv0.x << 16);
    float ky = __uint_as_float(kv0.x & 0xffff0000u);
    float part = kx * qv.x + ky * qv.y;
    part += __shfl_xor(part, 1, 64);
    part += __shfl_xor(part, 2, 64);
    part += __shfl_xor(part, 4, 64);
    float sc = part + b0;
    if (sc > m + 8.f) {
      float f = __expf(m - sc);
      d *= f; accx *= f; accy *= f;
      m = sc;
    }
    float p = __expf(sc - m);
    d += p;
    accx += p * __uint_as_float(kv0.y << 16);
    accy += p * __uint_as_float(kv0.y & 0xffff0000u);
  }

  float rd = (d > 0.f) ? 1.0f / d : 0.f;
  *(float2*)(out_pre + (size_t)node * DMODEL + l * 2) = make_float2(accx * rd, accy * rd);
}

// ---------------------------------------------------------------------------
// Launch
// ---------------------------------------------------------------------------
extern "C" void kernel_launch(void* const* d_in, const int* in_sizes, int n_in,
                              void* d_out, int out_size, void* d_ws, size_t ws_size,
                              hipStream_t stream) {
  const float* h_in  = (const float*)d_in[0];
  const int*   src   = (const int*)d_in[1];
  const int*   dst   = (const int*)d_in[2];
  const float* e_feat= (const float*)d_in[3];
  const float* Wq    = (const float*)d_in[4];
  const float* bq    = (const float*)d_in[5];
  const float* Wk    = (const float*)d_in[6];
  const float* bk    = (const float*)d_in[7];
  const float* Wv    = (const float*)d_in[8];
  const float* bv    = (const float*)d_in[9];
  const float* We    = (const float*)d_in[10];
  const float* be    = (const float*)d_in[11];
  const float* Wo    = (const float*)d_in[12];
  const float* bo    = (const float*)d_in[13];
  float* out = (float*)d_out;

  const int N = in_sizes[0] / DMODEL;
  const int E = in_sizes[1];

  char* ws = (char*)d_ws;
  size_t off = 0;
  auto alloc = [&](size_t bytes) {
    size_t o = off;
    off = (off + bytes + 255) & ~(size_t)255;
    return o;
  };
  float*           q          = (float*)(ws + alloc((size_t)N * DMODEL * 4));
  unsigned short*  kv         = (unsigned short*)(ws + alloc((size_t)N * 256 * 2));
  int*             counts     = (int*)(ws + alloc((size_t)N * 4));
  int*             row_start  = (int*)(ws + alloc((size_t)(N + 1) * 4));
  int*             partials   = (int*)(ws + alloc((size_t)64 * 4));
  int2*            pair_sorted= (int2*)(ws + alloc((size_t)E * 8));
  float*           bias_ed    = (float*)(ws + alloc((size_t)E * NHEAD * 4));
  float*           out_pre    = (float*)(ws + alloc((size_t)N * DMODEL * 4));
  unsigned short*  wpack      = (unsigned short*)(ws + alloc((size_t)4 * 32768 * 2));
  (void)ws_size;

  hipMemsetAsync(counts, 0, (size_t)N * 4, stream);

  const int gemmBlocks = (N + 63) / 64;
  const int scanBlocks = (N + 1023) / 1024;
  const int eBlocks = (E + 255) / 256;

  // Pack all four weights into MFMA fragment order (hi/lo split)
  pack_w_kernel<<<256, 256, 0, stream>>>(Wq, Wk, Wv, Wo, wpack);

  // QKV projections via MFMA (k gets the 0.25 scale folded; exact in bf16).
  // k and v write interleaved into the kv buffer.
  mfma_gemm_128<float, 0><<<gemmBlocks, 256, 0, stream>>>(
      h_in, wpack + 0 * 32768, bq, q, N, 1.0f);
  mfma_gemm_128<__hip_bfloat16, 1><<<gemmBlocks, 256, 0, stream>>>(
      h_in, wpack + 1 * 32768, bk, (__hip_bfloat16*)kv, N, 0.25f);
  mfma_gemm_128<__hip_bfloat16, 2><<<gemmBlocks, 256, 0, stream>>>(
      h_in, wpack + 2 * 32768, bv, (__hip_bfloat16*)kv, N, 1.0f);

  // Edge bias (coalesced) + CSR build (8B scatter)
  ebias_kernel<<<eBlocks, 256, 0, stream>>>(e_feat, We, be, bias_ed, E);
  count_kernel<<<eBlocks, 256, 0, stream>>>(dst, counts, E);
  scan1_kernel<<<scanBlocks, 1024, 0, stream>>>(counts, row_start, partials, N);
  scan2_kernel<<<1, 64, 0, stream>>>(partials, scanBlocks);
  scan3_kernel<<<scanBlocks, 1024, 0, stream>>>(row_start, partials, N);
  fill_kernel<<<eBlocks, 256, 0, stream>>>(dst, src, row_start, counts, pair_sorted, E);

  // Fused score + softmax + aggregate (one wave per node)
  fused_attn_kernel<<<(N + 3) / 4, 256, 0, stream>>>(
      kv, q, bias_ed, row_start, pair_sorted, out_pre, N);

  // Output projection via MFMA
  mfma_gemm_128<float, 0><<<gemmBlocks, 256, 0, stream>>>(
      out_pre, wpack + 3 * 32768, bo, out, N, 1.0f);
}